// Round 11
// baseline (322.815 us; speedup 1.0000x reference)
//
#include <hip/hip_runtime.h>

#define B_SZ 1024
#define D_SZ 128
#define KTERMS 7

typedef float vfloat4 __attribute__((ext_vector_type(4)));

__device__ inline float bflo(unsigned u) { return __uint_as_float(u << 16); }
__device__ inline float bfhi(unsigned u) { return __uint_as_float(u & 0xffff0000u); }

// J1 barrier: raw s_barrier, NO waitcnt, NO memory clobber -> compiler keeps
// global loads/stores pipelined across it (this is why __syncthreads is not
// used: it drains vmcnt(0) and would serialize the stream).
#define BAR_J1() asm volatile("s_barrier")
// J2 barrier: drain this wave's LDS ops, then barrier; memory clobber orders
// the compiler's ds accesses around it.
#define BAR_J2() asm volatile("s_waitcnt lgkmcnt(0)\ns_barrier" ::: "memory")

// 128-elem dot: full bf16-packed row (64 uints, REGISTERS) x LDS vector.
// Round A: all lanes read the same address (broadcast). Round B: 2 distinct
// addresses per instruction (2-way broadcast) -> conflict-free either way.
__device__ inline float dotR(const unsigned* R, const float* v) {
    float a0 = 0.f, a1 = 0.f, a2 = 0.f, a3 = 0.f;
#pragma unroll
    for (int j = 0; j < 32; ++j) {
        vfloat4 vv = *(const vfloat4*)(v + 4 * j);
        a0 = fmaf(bflo(R[2 * j]),     vv.x, a0);
        a1 = fmaf(bfhi(R[2 * j]),     vv.y, a1);
        a2 = fmaf(bflo(R[2 * j + 1]), vv.z, a2);
        a3 = fmaf(bfhi(R[2 * j + 1]), vv.w, a3);
    }
    return (a0 + a1) + (a2 + a3);
}

// One block (512 threads) per batch, WAVE-SPECIALIZED:
//   waves 0-3 (tid<256) : J1 — stream A0,W -> A1,A2 (coalesced, nontemporal)
//   waves 4-7 (tid>=256): J2 — y = expm(Omega) y0; thread owns full row of
//                         A0 (m=0) or W (m=1), bf16-packed in 64 uint regs.
// Both paths execute exactly 14 s_barriers, so every CU co-schedules streaming
// waves with latency-chain waves — no dispatch-order assumptions (r9 lesson),
// no machine-wide phase lockstep (r10 lesson).
__global__ void __launch_bounds__(512, 4)
magnus_kernel(const float* __restrict__ t0p, const float* __restrict__ hp,
              const float* __restrict__ y0, const float* __restrict__ A0,
              const float* __restrict__ W, float* __restrict__ out)
{
    __shared__ __align__(16) float svr[D_SZ];
    __shared__ __align__(16) float su1[D_SZ];
    __shared__ __align__(16) float su2[D_SZ];

    const int b   = blockIdx.x;
    const int tid = threadIdx.x;
    const float h  = hp[0];
    const float tb = t0p[b];
    const size_t moff = (size_t)b * (D_SZ * D_SZ);

    if (tid < 256) {
        // ================= J1: streaming =================
        const float SQ3_6 = 0.28867513459481287f;  // sqrt(3)/6
        const float t1 = tb + (0.5f - SQ3_6) * h;
        const float t2 = tb + (0.5f + SQ3_6) * h;
        const float4* A0v = (const float4*)(A0 + moff);
        const float4* Wv  = (const float4*)(W + moff);
        vfloat4* o1 = (vfloat4*)(out + (size_t)B_SZ * D_SZ + moff);
        vfloat4* o2 = (vfloat4*)(out + (size_t)B_SZ * D_SZ
                                     + (size_t)B_SZ * D_SZ * D_SZ + moff);
#pragma unroll
        for (int it = 0; it < 16; ++it) {
            int i = it * 256 + tid;   // float4 chunk 0..4095
            float4 a = A0v[i];
            float4 w = Wv[i];
            vfloat4 p1, p2;
            p1.x = fmaf(t1, w.x, a.x); p1.y = fmaf(t1, w.y, a.y);
            p1.z = fmaf(t1, w.z, a.z); p1.w = fmaf(t1, w.w, a.w);
            p2.x = fmaf(t2, w.x, a.x); p2.y = fmaf(t2, w.y, a.y);
            p2.z = fmaf(t2, w.z, a.z); p2.w = fmaf(t2, w.w, a.w);
            __builtin_nontemporal_store(p1, o1 + i);
            __builtin_nontemporal_store(p2, o2 + i);
            if (it >= 1 && it <= 14) BAR_J1();   // 14 barriers, matched w/ J2
        }
    } else {
        // ================= J2: expm chain =================
        const int tl = tid - 256;
        const int m  = tl & 1;        // 0 = A0 row, 1 = W row
        const int r  = tl >> 1;       // 0..127
        const float* rowp = (m ? W : A0) + moff + (size_t)r * D_SZ;

        // load full row, pack to bf16 regs (asm output: not rematerializable)
        unsigned R[64];
#pragma unroll
        for (int j = 0; j < 32; ++j) {
            float4 x = ((const float4*)rowp)[j];
            asm("v_cvt_pk_bf16_f32 %0, %1, %2" : "=v"(R[2*j])   : "v"(x.x), "v"(x.y));
            asm("v_cvt_pk_bf16_f32 %0, %1, %2" : "=v"(R[2*j+1]) : "v"(x.z), "v"(x.w));
        }

        float yv = y0[(size_t)b * D_SZ + r];
        if (m == 0) svr[r] = yv;
        float yacc = yv;
        BAR_J2();   // barrier #1

        const float hs = h * (tb + 0.5f * h);           // h * s
        const float c3 = h * h * h * (1.0f / 12.0f);    // h^3 / 12
        // KTERMS=7: ||Omega|| <~ 0.4 -> truncation ~1e-7, invisible vs bf16.

#pragma unroll
        for (int k = 1; k <= KTERMS; ++k) {
            // Round A: m=0 lanes -> u1[r] = A0_r . v ; m=1 -> u2[r] = W_r . v
            float ownA = dotR(R, svr);
            if (m == 0) su1[r] = ownA; else su2[r] = ownA;
            BAR_J2();                              // barriers #2,4,..,14
            // Round B: m=0 -> u3[r] = A0_r . u2 ; m=1 -> u4[r] = W_r . u1
            float ownB = dotR(R, m ? su1 : su2);
            // partner (lane^1) holds the complementary pair -> fuse in-register
            float othA = __shfl_xor(ownA, 1);
            float othB = __shfl_xor(ownB, 1);
            float u1 = m ? othA : ownA;
            float u2 = m ? ownA : othA;
            float u3 = m ? othB : ownB;
            float u4 = m ? ownB : othB;
            float wn = (h * u1 + hs * u2 - c3 * (u3 - u4)) * (1.0f / (float)k);
            yacc += wn;
            if (k < KTERMS) {
                if (m == 0) svr[r] = wn;
                BAR_J2();                          // barriers #3,5,..,13
            }
        }

        if (m == 0) {
            out[(size_t)b * D_SZ + r] = yacc;
        }
    }
}

extern "C" void kernel_launch(void* const* d_in, const int* in_sizes, int n_in,
                              void* d_out, int out_size, void* d_ws, size_t ws_size,
                              hipStream_t stream) {
    const float* t0 = (const float*)d_in[0];
    const float* h  = (const float*)d_in[1];
    const float* y0 = (const float*)d_in[2];
    const float* A0 = (const float*)d_in[3];
    const float* W  = (const float*)d_in[4];
    float* out = (float*)d_out;
    magnus_kernel<<<B_SZ, 512, 0, stream>>>(t0, h, y0, A0, W, out);
}

// Round 12
// 269.695 us; speedup vs baseline: 1.1970x; 1.1970x over previous
//
#include <hip/hip_runtime.h>

#define B_SZ 1024
#define D_SZ 128
#define KTERMS 7
#define QPAD 36   // floats per quarter-segment: 32 data + 4 pad -> conflict-free quarters
#define NSLOT 2048  // per-CU ticket slots (xcc[3b] x hwid[15:8])

typedef float vfloat4 __attribute__((ext_vector_type(4)));

__device__ inline float bflo(unsigned u) { return __uint_as_float(u << 16); }
__device__ inline float bfhi(unsigned u) { return __uint_as_float(u & 0xffff0000u); }

// dual 32-elem dot sharing ONE vector read
__device__ inline void dot32x2(const unsigned* ra, const unsigned* rw,
                               const float* v, float& oa, float& ow) {
    float a0=0.f,a1=0.f,a2=0.f,a3=0.f, w0=0.f,w1=0.f,w2=0.f,w3=0.f;
#pragma unroll
    for (int j = 0; j < 8; ++j) {
        vfloat4 vv = *(const vfloat4*)(v + 4 * j);
        a0 = fmaf(bflo(ra[2*j]),   vv.x, a0);
        a1 = fmaf(bfhi(ra[2*j]),   vv.y, a1);
        a2 = fmaf(bflo(ra[2*j+1]), vv.z, a2);
        a3 = fmaf(bfhi(ra[2*j+1]), vv.w, a3);
        w0 = fmaf(bflo(rw[2*j]),   vv.x, w0);
        w1 = fmaf(bfhi(rw[2*j]),   vv.y, w1);
        w2 = fmaf(bflo(rw[2*j+1]), vv.z, w2);
        w3 = fmaf(bfhi(rw[2*j+1]), vv.w, w3);
    }
    oa = (a0 + a1) + (a2 + a3);
    ow = (w0 + w1) + (w2 + w3);
}

__device__ inline float dot32(const unsigned* rq, const float* v) {
    float a0=0.f,a1=0.f,a2=0.f,a3=0.f;
#pragma unroll
    for (int j = 0; j < 8; ++j) {
        vfloat4 vv = *(const vfloat4*)(v + 4 * j);
        a0 = fmaf(bflo(rq[2*j]),   vv.x, a0);
        a1 = fmaf(bfhi(rq[2*j]),   vv.y, a1);
        a2 = fmaf(bflo(rq[2*j+1]), vv.z, a2);
        a3 = fmaf(bfhi(rq[2*j+1]), vv.w, a3);
    }
    return (a0 + a1) + (a2 + a3);
}

// 2048 blocks, job chosen at runtime per physical CU:
//   ticket = atomicAdd(cu_counter[my_cu]); job = ticket & 1
//   -> blocks resident on a CU alternate J1/J2 in ARRIVAL order, independent
//      of dispatch policy (r9's blockIdx-parity starved even CUs of J2).
//   J1 (even): stream A1,A2 (r9's clean coalesced nontemporal path).
//   J2 (odd):  y = expm(Omega) y0 (r10's fused quarter-row register chain).
// Batch index from two global queues with overflow fallback (exact coverage).
__global__ void __launch_bounds__(512, 4)
magnus_kernel(const float* __restrict__ t0p, const float* __restrict__ hp,
              const float* __restrict__ y0, const float* __restrict__ A0,
              const float* __restrict__ W, float* __restrict__ out,
              int* __restrict__ ws)
{
    __shared__ __align__(16) float svr [4 * QPAD];
    __shared__ __align__(16) float su1r[4 * QPAD];
    __shared__ __align__(16) float su2r[4 * QPAD];
    __shared__ int sjob, sb;

    const int tid = threadIdx.x;

    if (tid == 0) {
        unsigned hwid, xcc;
        asm volatile("s_getreg_b32 %0, hwreg(HW_REG_HW_ID)" : "=s"(hwid));
        asm volatile("s_getreg_b32 %0, hwreg(HW_REG_XCC_ID)" : "=s"(xcc));
        int slot = ((xcc & 7) << 8) | ((hwid >> 8) & 0xFF);  // SE|SH|CU bits
        int ticket = atomicAdd(&ws[slot], 1);
        int job = ticket & 1;
        int b = atomicAdd(&ws[NSLOT + job], 1);
        if (b >= B_SZ) {               // this job's queue exhausted -> other
            job ^= 1;
            b = atomicAdd(&ws[NSLOT + job], 1);
        }
        sjob = job;
        sb = (b < B_SZ) ? b : -1;
    }
    __syncthreads();
    const int job = sjob;
    const int b = sb;
    if (b < 0) return;                 // all work claimed (can't happen, guard)

    const float h  = hp[0];
    const float tb = t0p[b];
    const size_t moff = (size_t)b * (D_SZ * D_SZ);

    if (job == 0) {
        // ================= J1: stream A1, A2 =================
        const float SQ3_6 = 0.28867513459481287f;  // sqrt(3)/6
        const float t1 = tb + (0.5f - SQ3_6) * h;
        const float t2 = tb + (0.5f + SQ3_6) * h;
        const float4* A0v = (const float4*)(A0 + moff);
        const float4* Wv  = (const float4*)(W + moff);
        vfloat4* o1 = (vfloat4*)(out + (size_t)B_SZ * D_SZ + moff);
        vfloat4* o2 = (vfloat4*)(out + (size_t)B_SZ * D_SZ
                                     + (size_t)B_SZ * D_SZ * D_SZ + moff);
#pragma unroll 8
        for (int it = 0; it < 8; ++it) {
            int i = it * 512 + tid;
            float4 a = A0v[i];
            float4 w = Wv[i];
            vfloat4 p1, p2;
            p1.x = fmaf(t1, w.x, a.x); p1.y = fmaf(t1, w.y, a.y);
            p1.z = fmaf(t1, w.z, a.z); p1.w = fmaf(t1, w.w, a.w);
            p2.x = fmaf(t2, w.x, a.x); p2.y = fmaf(t2, w.y, a.y);
            p2.z = fmaf(t2, w.z, a.z); p2.w = fmaf(t2, w.w, a.w);
            __builtin_nontemporal_store(p1, o1 + i);
            __builtin_nontemporal_store(p2, o2 + i);
        }
        return;
    }

    // ================= J2: y = expm(Omega) y0 =================
    // Thread owns quarter-row (32 elems) of BOTH A0,W, bf16-packed in regs.
    // Second read of A0,W: L3-served (r9 measured FETCH ~70MB). No big stores.
    const int row = tid >> 2;     // 0..127
    const int q   = tid & 3;      // quarter 0..3
    const int fbase = row * 32 + q * 8;   // float4 index of thread's 128B chunk

    const float4* Ap = (const float4*)(A0 + moff) + fbase;
    const float4* Wp = (const float4*)(W + moff) + fbase;
    unsigned ra[16], rw[16];
#pragma unroll
    for (int it = 0; it < 8; ++it) {
        float4 a = Ap[it];
        float4 w = Wp[it];
        asm("v_cvt_pk_bf16_f32 %0, %1, %2" : "=v"(ra[2*it])   : "v"(a.x), "v"(a.y));
        asm("v_cvt_pk_bf16_f32 %0, %1, %2" : "=v"(ra[2*it+1]) : "v"(a.z), "v"(a.w));
        asm("v_cvt_pk_bf16_f32 %0, %1, %2" : "=v"(rw[2*it])   : "v"(w.x), "v"(w.y));
        asm("v_cvt_pk_bf16_f32 %0, %1, %2" : "=v"(rw[2*it+1]) : "v"(w.z), "v"(w.w));
    }

    float yacc = y0[(size_t)b * D_SZ + row];   // 4-lane broadcast read
    if (tid < D_SZ) {
        svr[(tid >> 5) * QPAD + (tid & 31)] = y0[(size_t)b * D_SZ + tid];
    }
    __syncthreads();

    const float hs = h * (tb + 0.5f * h);           // h * s
    const float c3 = h * h * h * (1.0f / 12.0f);    // h^3 / 12
    const int uflat = (row >> 5) * QPAD + (row & 31);
    // KTERMS=7: ||Omega|| <~ 0.4 -> truncation ~1e-7, invisible vs bf16 noise.

#pragma unroll
    for (int k = 1; k <= KTERMS; ++k) {
        // Round A: u1 = A0 v, u2 = W v  (one shared v-read)
        float pa, pw;
        dot32x2(ra, rw, svr + q * QPAD, pa, pw);
        pa += __shfl_xor(pa, 1); pa += __shfl_xor(pa, 2);
        pw += __shfl_xor(pw, 1); pw += __shfl_xor(pw, 2);
        if (q == 0) { su1r[uflat] = pa; su2r[uflat] = pw; }
        __syncthreads();
        // Round B: u3 = A0 u2, u4 = W u1
        float pb = dot32(ra, su2r + q * QPAD);
        float pc = dot32(rw, su1r + q * QPAD);
        pb += __shfl_xor(pb, 1); pb += __shfl_xor(pb, 2);
        pc += __shfl_xor(pc, 1); pc += __shfl_xor(pc, 2);
        // fused update: every thread holds full u1..u4 of its row
        float wn = (h * pa + hs * pw - c3 * (pb - pc)) * (1.0f / (float)k);
        yacc += wn;
        if (k < KTERMS) {
            if (q == 0) svr[uflat] = wn;
            __syncthreads();
        }
    }

    if (q == 0) {
        out[(size_t)b * D_SZ + row] = yacc;
    }
}

extern "C" void kernel_launch(void* const* d_in, const int* in_sizes, int n_in,
                              void* d_out, int out_size, void* d_ws, size_t ws_size,
                              hipStream_t stream) {
    const float* t0 = (const float*)d_in[0];
    const float* h  = (const float*)d_in[1];
    const float* y0 = (const float*)d_in[2];
    const float* A0 = (const float*)d_in[3];
    const float* W  = (const float*)d_in[4];
    float* out = (float*)d_out;
    // zero per-CU ticket counters + 2 batch queues (graph-capture-safe async op)
    hipMemsetAsync(d_ws, 0, (NSLOT + 2) * sizeof(int), stream);
    magnus_kernel<<<2 * B_SZ, 512, 0, stream>>>(t0, h, y0, A0, W, out,
                                                (int*)d_ws);
}